// Round 10
// baseline (195.522 us; speedup 1.0000x reference)
//
#include <hip/hip_runtime.h>
#include <hip/hip_bf16.h>

#define NQH 64
#define NKVH 8
#define DH 64
#define SEQ 1024
#define HID 2880
#define QKV_N 5120   // (NQ+2*NKV)*DH
#define ATTN_N 4096  // NQ*DH
#define WIN 128
#define WO_NPAD 2944 // 46 n-tiles of 64
#define SCALE_F 0.125f

typedef __attribute__((ext_vector_type(8))) __bf16 bf16x8;
typedef __attribute__((ext_vector_type(4))) float f32x4;

#define GLOAD_LDS16(g, l) \
    __builtin_amdgcn_global_load_lds((const __attribute__((address_space(1))) void*)(g), \
                                     (__attribute__((address_space(3))) void*)(l), 16, 0, 0)

__device__ __forceinline__ ushort f2bf(float x) {
    union { float f; unsigned int u; } c; c.f = x;
    unsigned int u = c.u;
    unsigned int r = (u + 0x7FFFu + ((u >> 16) & 1u)) >> 16;
    return (ushort)r;
}

// ---------------------------------------------------------------- convert (plain)
__global__ __launch_bounds__(256) void convert_f32_bf16(
    const float* __restrict__ in, ushort* __restrict__ out, int n4)
{
    int idx = blockIdx.x * blockDim.x + threadIdx.x;
    int stride = gridDim.x * blockDim.x;
    for (int i = idx; i < n4; i += stride) {
        float4 v = reinterpret_cast<const float4*>(in)[i];
        ushort4 o;
        o.x = f2bf(v.x); o.y = f2bf(v.y); o.z = f2bf(v.z); o.w = f2bf(v.w);
        reinterpret_cast<ushort4*>(out)[i] = o;
    }
}

// ---------------------------------------------------------------- transpose+convert
// in: [K][N] f32  ->  out: [Npad][K] bf16 (rows >= N zero-filled). K,Npad multiples of 64.
__global__ __launch_bounds__(256) void transpose_convert(
    const float* __restrict__ in, ushort* __restrict__ out, int K, int N)
{
    __shared__ ushort tile[64][80];   // row stride 160B (16B-aligned for uint4)
    const int bk = blockIdx.x * 64;   // k tile origin
    const int bn = blockIdx.y * 64;   // n tile origin
    const int tid = threadIdx.x;
    const bool inb = bn < N;          // whole tile valid or whole tile pad (N % 64 == 0)

#pragma unroll
    for (int it = 0; it < 4; ++it) {
        int r = it * 16 + (tid >> 4);         // k offset 0..63
        int c4 = (tid & 15) * 4;              // n offset
        float4 v = make_float4(0.f, 0.f, 0.f, 0.f);
        if (inb) v = *(const float4*)&in[(size_t)(bk + r) * N + bn + c4];
        tile[c4 + 0][r] = f2bf(v.x);
        tile[c4 + 1][r] = f2bf(v.y);
        tile[c4 + 2][r] = f2bf(v.z);
        tile[c4 + 3][r] = f2bf(v.w);
    }
    __syncthreads();
#pragma unroll
    for (int it = 0; it < 2; ++it) {
        int nr = it * 32 + (tid >> 3);        // n offset 0..63
        int c8 = (tid & 7) * 8;               // k offset
        uint4 v = *(const uint4*)&tile[nr][c8];
        *(uint4*)&out[(size_t)(bn + nr) * K + bk + c8] = v;
    }
}

// ---------------------------------------------------------------- barrier-free wave GEMM
// One 64-thread block = ONE WAVE owning a 64x64 output tile with a private 32 KB
// double-buffered LDS pipeline. Per K-step (BK=64): issue 16 global_load_lds for tile
// t+2's buffer, s_waitcnt vmcnt(16) proves tile t landed (its 16 loads are the oldest),
// 16 ds_read_b128, 32 MFMA. ZERO s_barrier: no cross-wave coupling, so every wave keeps
// 16-32 KB permanently in flight; 5 resident blocks/CU sustain ~100+ KB/CU in flight
// (R5-R9 lesson: barrier lockstep collapsed in-flight bytes; TLP/sync tweaks were null).
// LDS row = 64 el = 128 B; slot swizzle = chunk ^ (row&7) (measured 0-conflict family);
// staging: 8 rows x 128 B per inst, full-line coalesced, inverse-swizzled source.
template<bool ROPE>
__global__ __launch_bounds__(64) void gemm_wave(
    const ushort* __restrict__ A, const ushort* __restrict__ BT,
    const float* __restrict__ bias, float* __restrict__ C,
    int K, int ldC, int Nreal,
    const float* __restrict__ cosp, const float* __restrict__ sinp)
{
    __shared__ ushort Al[2 * 4096];   // 2 x 8 KB (64 x 64)
    __shared__ ushort Bl[2 * 4096];   // 2 x 8 KB
    const int lane = threadIdx.x;     // 0..63
    const int g4 = lane >> 4;
    const int r15 = lane & 15;

    // bijective XCD swizzle (nwg % 8 == 0); m-major within XCD (16 m-tiles per n-tile)
    const int flat = blockIdx.x + gridDim.x * blockIdx.y;
    const int per = (gridDim.x * gridDim.y) >> 3;
    const int virt = (flat & 7) * per + (flat >> 3);
    const int m0 = (virt & 15) * 64;
    const int n0 = (virt >> 4) * 64;

    // ---- per-lane staging source base (inverse-swizzled; identical form for A and B)
    // inst i, lane l -> row = i*8 + (l>>3), stored slot = l&7, global chunk = (l&7)^(l>>3)
    const int srow = lane >> 3;
    const int sch = (lane & 7) ^ srow;
    const ushort* aBase = A  + (size_t)(m0 + srow) * K + sch * 8;
    const ushort* bBase = BT + (size_t)(n0 + srow) * K + sch * 8;
    const size_t rstep = (size_t)8 * K;   // +8 rows per staging inst

#define STAGE_TILE(buf) do { \
        const ushort* ap_ = aBase; const ushort* bp_ = bBase; \
        _Pragma("unroll") \
        for (int i_ = 0; i_ < 8; ++i_) { \
            GLOAD_LDS16(ap_, &Al[(buf) * 4096 + i_ * 512]); \
            GLOAD_LDS16(bp_, &Bl[(buf) * 4096 + i_ * 512]); \
            ap_ += rstep; bp_ += rstep; \
        } \
        aBase += 64; bBase += 64; \
    } while (0)

    // ---- fragment read offsets (element units), swizzled to match staging
    int aoff[4][2], boff[4][2];
#pragma unroll
    for (int i = 0; i < 4; ++i)
#pragma unroll
        for (int ks = 0; ks < 2; ++ks) {
            int row = i * 16 + r15;           // same form for A rows and B cols
            int slot = (ks * 4 + g4) ^ (row & 7);
            aoff[i][ks] = row * 64 + slot * 8;
            boff[i][ks] = row * 64 + slot * 8;
        }

    f32x4 acc[4][4];
#pragma unroll
    for (int mi = 0; mi < 4; ++mi)
#pragma unroll
        for (int ni = 0; ni < 4; ++ni) acc[mi][ni] = (f32x4){0.f, 0.f, 0.f, 0.f};

#define COMPUTE_TILE(buf) do { \
        const ushort* Ab = &Al[(buf) * 4096]; \
        const ushort* Bb = &Bl[(buf) * 4096]; \
        _Pragma("unroll") \
        for (int ks = 0; ks < 2; ++ks) { \
            bf16x8 a0 = *(const bf16x8*)&Ab[aoff[0][ks]]; \
            bf16x8 a1 = *(const bf16x8*)&Ab[aoff[1][ks]]; \
            bf16x8 a2 = *(const bf16x8*)&Ab[aoff[2][ks]]; \
            bf16x8 a3 = *(const bf16x8*)&Ab[aoff[3][ks]]; \
            bf16x8 b0 = *(const bf16x8*)&Bb[boff[0][ks]]; \
            bf16x8 b1 = *(const bf16x8*)&Bb[boff[1][ks]]; \
            bf16x8 b2 = *(const bf16x8*)&Bb[boff[2][ks]]; \
            bf16x8 b3 = *(const bf16x8*)&Bb[boff[3][ks]]; \
            acc[0][0] = __builtin_amdgcn_mfma_f32_16x16x32_bf16(a0, b0, acc[0][0], 0, 0, 0); \
            acc[0][1] = __builtin_amdgcn_mfma_f32_16x16x32_bf16(a0, b1, acc[0][1], 0, 0, 0); \
            acc[0][2] = __builtin_amdgcn_mfma_f32_16x16x32_bf16(a0, b2, acc[0][2], 0, 0, 0); \
            acc[0][3] = __builtin_amdgcn_mfma_f32_16x16x32_bf16(a0, b3, acc[0][3], 0, 0, 0); \
            acc[1][0] = __builtin_amdgcn_mfma_f32_16x16x32_bf16(a1, b0, acc[1][0], 0, 0, 0); \
            acc[1][1] = __builtin_amdgcn_mfma_f32_16x16x32_bf16(a1, b1, acc[1][1], 0, 0, 0); \
            acc[1][2] = __builtin_amdgcn_mfma_f32_16x16x32_bf16(a1, b2, acc[1][2], 0, 0, 0); \
            acc[1][3] = __builtin_amdgcn_mfma_f32_16x16x32_bf16(a1, b3, acc[1][3], 0, 0, 0); \
            acc[2][0] = __builtin_amdgcn_mfma_f32_16x16x32_bf16(a2, b0, acc[2][0], 0, 0, 0); \
            acc[2][1] = __builtin_amdgcn_mfma_f32_16x16x32_bf16(a2, b1, acc[2][1], 0, 0, 0); \
            acc[2][2] = __builtin_amdgcn_mfma_f32_16x16x32_bf16(a2, b2, acc[2][2], 0, 0, 0); \
            acc[2][3] = __builtin_amdgcn_mfma_f32_16x16x32_bf16(a2, b3, acc[2][3], 0, 0, 0); \
            acc[3][0] = __builtin_amdgcn_mfma_f32_16x16x32_bf16(a3, b0, acc[3][0], 0, 0, 0); \
            acc[3][1] = __builtin_amdgcn_mfma_f32_16x16x32_bf16(a3, b1, acc[3][1], 0, 0, 0); \
            acc[3][2] = __builtin_amdgcn_mfma_f32_16x16x32_bf16(a3, b2, acc[3][2], 0, 0, 0); \
            acc[3][3] = __builtin_amdgcn_mfma_f32_16x16x32_bf16(a3, b3, acc[3][3], 0, 0, 0); \
        } \
    } while (0)

    const int NT = K >> 6;
    STAGE_TILE(0);                       // tile 0 (16 loads in flight)
    STAGE_TILE(1);                       // tile 1 (32 in flight)
    for (int kt = 0; kt < NT; ++kt) {
        if (kt + 1 < NT) {
            asm volatile("s_waitcnt vmcnt(16)" ::: "memory");  // tile kt (oldest 16) landed
        } else {
            asm volatile("s_waitcnt vmcnt(0)" ::: "memory");   // final tile
        }
        __builtin_amdgcn_sched_barrier(0);
        COMPUTE_TILE(kt & 1);
        if (kt + 2 < NT) {
            asm volatile("s_waitcnt lgkmcnt(0)" ::: "memory"); // this buf's ds_reads done
            __builtin_amdgcn_sched_barrier(0);
            STAGE_TILE(kt & 1);          // restage freed buffer for tile kt+2
        }
    }
#undef STAGE_TILE
#undef COMPUTE_TILE

    // ---- epilogue: bias + optional fused RoPE in-place on acc, f32 store
    // D frag: row = g4*4 + r (+16*mi +m0), col = r15 (+16*ni +n0)
#pragma unroll
    for (int ni = 0; ni < 4; ++ni) {
        int col = n0 + ni * 16 + r15;
        float bv = (col < Nreal) ? bias[col] : 0.f;
#pragma unroll
        for (int mi = 0; mi < 4; ++mi)
#pragma unroll
            for (int r = 0; r < 4; ++r) acc[mi][ni][r] += bv;
    }
    if (ROPE) {
        const int head = n0 >> 6;        // wave = exactly one 64-col head
        if (head < 72) {                 // q heads 0..63, k heads 64..71; v passthrough
#pragma unroll
            for (int mi = 0; mi < 4; ++mi)
#pragma unroll
                for (int r = 0; r < 4; ++r) {
                    int q = m0 + mi * 16 + g4 * 4 + r;
#pragma unroll
                    for (int dp = 0; dp < 2; ++dp) {
                        int d = dp * 16 + r15;
                        float c = cosp[q * 32 + d];
                        float s = sinp[q * 32 + d];
                        float x1 = acc[mi][dp][r];
                        float x2 = acc[mi][dp + 2][r];
                        acc[mi][dp][r]     = x1 * c - x2 * s;
                        acc[mi][dp + 2][r] = x2 * c + x1 * s;
                    }
                }
        }
    }
#pragma unroll
    for (int ni = 0; ni < 4; ++ni) {
        int col = n0 + ni * 16 + r15;
        if (col < Nreal) {
#pragma unroll
            for (int mi = 0; mi < 4; ++mi) {
                int row = m0 + mi * 16 + g4 * 4;
#pragma unroll
                for (int r = 0; r < 4; ++r)
                    C[(size_t)(row + r) * ldC + col] = acc[mi][ni][r];
            }
        }
    }
}

// ---------------------------------------------------------------- MFMA flash attention
__global__ __launch_bounds__(512) void attn_mfma_kernel(
    const float* __restrict__ qkv, const float* __restrict__ sinks,
    ushort* __restrict__ attn_out)
{
    __shared__ __align__(16) ushort Kl[160][72];    // [key][d], pad 64->72 (2-way free)
    __shared__ __align__(16) ushort Vt[64][168];    // [d][key], pad 160->168 (2-way free)
    __shared__ __align__(16) ushort Pl[8][32][40];  // per-wave P chunk [row][32 keys], pad->40
    const int t = threadIdx.x;
    const int w = t >> 6;
    const int l = t & 63;
    const int g4 = l >> 4;
    const int r15 = l & 15;
    const int q0 = blockIdx.x * 32;
    const int hk = blockIdx.y;
    const int kbase = q0 - 128;

    // ---- stage K [160][64] f32->bf16 and V^T [64][160]
#pragma unroll
    for (int i = 0; i < 5; ++i) {
        int idx = i * 512 + t;             // 0..2559
        int row = idx >> 4;                // 0..159
        int c4 = (idx & 15) * 4;           // 0..60
        int j = kbase + row;
        float4 kv = make_float4(0.f, 0.f, 0.f, 0.f);
        float4 vv = make_float4(0.f, 0.f, 0.f, 0.f);
        if (j >= 0) {
            kv = *(const float4*)&qkv[(size_t)j * QKV_N + 4096 + hk * 64 + c4];
            vv = *(const float4*)&qkv[(size_t)j * QKV_N + 4608 + hk * 64 + c4];
        }
        ushort4 kp;
        kp.x = f2bf(kv.x); kp.y = f2bf(kv.y); kp.z = f2bf(kv.z); kp.w = f2bf(kv.w);
        *(ushort4*)&Kl[row][c4] = kp;
        Vt[c4 + 0][row] = f2bf(vv.x);
        Vt[c4 + 1][row] = f2bf(vv.y);
        Vt[c4 + 2][row] = f2bf(vv.z);
        Vt[c4 + 3][row] = f2bf(vv.w);
    }

    // ---- Q fragments (B operand: lane supplies col = score-row = r15+16ct, k = d)
    bf16x8 qf[2][2];
#pragma unroll
    for (int ct = 0; ct < 2; ++ct) {
        int R = w * 32 + ct * 16 + r15;
        int q = q0 + (R & 31);
        int hq = hk * 8 + (R >> 5);
        const float* qb = &qkv[(size_t)q * QKV_N + hq * 64];
#pragma unroll
        for (int s = 0; s < 2; ++s) {
            float4 a = *(const float4*)&qb[s * 32 + g4 * 8];
            float4 b = *(const float4*)&qb[s * 32 + g4 * 8 + 4];
            union { ushort u[8]; bf16x8 v; } pk;
            pk.u[0] = f2bf(a.x * SCALE_F); pk.u[1] = f2bf(a.y * SCALE_F);
            pk.u[2] = f2bf(a.z * SCALE_F); pk.u[3] = f2bf(a.w * SCALE_F);
            pk.u[4] = f2bf(b.x * SCALE_F); pk.u[5] = f2bf(b.y * SCALE_F);
            pk.u[6] = f2bf(b.z * SCALE_F); pk.u[7] = f2bf(b.w * SCALE_F);
            qf[ct][s] = pk.v;
        }
    }
    __syncthreads();

    // ---- S^T = K @ Q^T : D row = key = 16kt+4g4+r, col = score-row = 16ct+r15 (+32w)
    f32x4 sc[10][2];
#pragma unroll
    for (int kt = 0; kt < 10; ++kt) {
        sc[kt][0] = (f32x4){0.f, 0.f, 0.f, 0.f};
        sc[kt][1] = (f32x4){0.f, 0.f, 0.f, 0.f};
    }
#pragma unroll
    for (int kt = 0; kt < 10; ++kt) {
#pragma unroll
        for (int s = 0; s < 2; ++s) {
            bf16x8 kf = *(const bf16x8*)&Kl[kt * 16 + r15][s * 32 + g4 * 8];
            sc[kt][0] = __builtin_amdgcn_mfma_f32_16x16x32_bf16(kf, qf[0][s], sc[kt][0], 0, 0, 0);
            sc[kt][1] = __builtin_amdgcn_mfma_f32_16x16x32_bf16(kf, qf[1][s], sc[kt][1], 0, 0, 0);
        }
    }

    // ---- masked softmax, per score-row; fold sink and 1/denom (all lane-local)
    const int minkey = 128 - q0;          // key_local >= minkey  <=>  j >= 0
#pragma unroll
    for (int ct = 0; ct < 2; ++ct) {
        int R = w * 32 + ct * 16 + r15;
        int ql = R & 31;
        float snk = sinks[hk * 8 + (R >> 5)];
#pragma unroll
        for (int kt = 0; kt < 10; ++kt)
#pragma unroll
            for (int r = 0; r < 4; ++r) {
                int key = kt * 16 + g4 * 4 + r;
                // allowed: q_local < key <= q_local+128 (window+causal), key >= minkey (j>=0)
                bool ok = (key > ql) && (key <= ql + 128) && (key >= minkey);
                if (!ok) sc[kt][ct][r] = -1e30f;
            }
        float m = snk;
#pragma unroll
        for (int kt = 0; kt < 10; ++kt)
#pragma unroll
            for (int r = 0; r < 4; ++r) m = fmaxf(m, sc[kt][ct][r]);
        m = fmaxf(m, __shfl_xor(m, 16));
        m = fmaxf(m, __shfl_xor(m, 32));
        float sum = 0.f;
#pragma unroll
        for (int kt = 0; kt < 10; ++kt)
#pragma unroll
            for (int r = 0; r < 4; ++r) {
                float p = __expf(sc[kt][ct][r] - m);
                sc[kt][ct][r] = p;
                sum += p;
            }
        sum += __shfl_xor(sum, 16);
        sum += __shfl_xor(sum, 32);
        sum += __expf(snk - m);
        float iv = 1.0f / sum;
#pragma unroll
        for (int kt = 0; kt < 10; ++kt)
#pragma unroll
            for (int r = 0; r < 4; ++r) sc[kt][ct][r] *= iv;
    }

    // ---- PV: out[row][d] = sum_key P[row][key] * V[key][d]
    f32x4 pv[2][4];
#pragma unroll
    for (int mi = 0; mi < 2; ++mi)
#pragma unroll
        for (int ni = 0; ni < 4; ++ni) pv[mi][ni] = (f32x4){0.f, 0.f, 0.f, 0.f};

#pragma unroll
    for (int s = 0; s < 5; ++s) {
#pragma unroll
        for (int ct = 0; ct < 2; ++ct)
#pragma unroll
            for (int kh = 0; kh < 2; ++kh) {
                int kt = 2 * s + kh;
                ushort4 p4;
                p4.x = f2bf(sc[kt][ct][0]);
                p4.y = f2bf(sc[kt][ct][1]);
                p4.z = f2bf(sc[kt][ct][2]);
                p4.w = f2bf(sc[kt][ct][3]);
                *(ushort4*)&Pl[w][ct * 16 + r15][kh * 16 + g4 * 4] = p4;
            }
#pragma unroll
        for (int mi = 0; mi < 2; ++mi) {
            bf16x8 pf = *(const bf16x8*)&Pl[w][mi * 16 + r15][g4 * 8];
#pragma unroll
            for (int ni = 0; ni < 4; ++ni) {
                bf16x8 vf = *(const bf16x8*)&Vt[ni * 16 + r15][s * 32 + g4 * 8];
                pv[mi][ni] = __builtin_amdgcn_mfma_f32_16x16x32_bf16(pf, vf, pv[mi][ni], 0, 0, 0);
            }
        }
    }

    // ---- write attn output (bf16): D row = 16mi+4g4+r (+32w), col = d = 16ni+r15
#pragma unroll
    for (int mi = 0; mi < 2; ++mi)
#pragma unroll
        for (int r = 0; r < 4; ++r) {
            int R = w * 32 + mi * 16 + g4 * 4 + r;
            int q = q0 + (R & 31);
            int hq = hk * 8 + (R >> 5);
            ushort* ob = &attn_out[(size_t)q * ATTN_N + hq * 64 + r15];
#pragma unroll
            for (int ni = 0; ni < 4; ++ni)
                ob[ni * 16] = f2bf(pv[mi][ni][r]);
        }
}

// ---------------------------------------------------------------- launch
extern "C" void kernel_launch(void* const* d_in, const int* in_sizes, int n_in,
                              void* d_out, int out_size, void* d_ws, size_t ws_size,
                              hipStream_t stream)
{
    const float* hidden = (const float*)d_in[0];
    const float* cosp   = (const float*)d_in[1];
    const float* sinp   = (const float*)d_in[2];
    const float* w_qkv  = (const float*)d_in[3];
    const float* b_qkv  = (const float*)d_in[4];
    const float* w_o    = (const float*)d_in[5];
    const float* b_o    = (const float*)d_in[6];
    const float* sinks  = (const float*)d_in[7];
    // d_in[8]=k_cache, d_in[9]=v_cache (zero), d_in[10]=kv_len (==0): unused.

    char* ws = (char*)d_ws;
    size_t off = 0;
    ushort* wqkvT = (ushort*)(ws + off); off += (size_t)QKV_N * HID * 2;      // [5120][2880]
    ushort* woT   = (ushort*)(ws + off); off += (size_t)WO_NPAD * ATTN_N * 2; // [2944][4096]
    float*  qkv   = (float*)(ws + off);  off += (size_t)SEQ * QKV_N * 4;
    // union region: hidden_b (gemm1 A) then attn_b (gemm2 A) — lifetimes disjoint
    ushort* hidden_b = (ushort*)(ws + off);
    ushort* attn_b   = (ushort*)(ws + off); off += (size_t)SEQ * ATTN_N * 2;
    if (off > ws_size) return;  // fail visibly rather than corrupt

    // weight transposes + hidden convert
    transpose_convert<<<dim3(HID / 64, QKV_N / 64), 256, 0, stream>>>(w_qkv, wqkvT, HID, QKV_N);
    transpose_convert<<<dim3(ATTN_N / 64, WO_NPAD / 64), 256, 0, stream>>>(w_o, woT, ATTN_N, HID);
    convert_f32_bf16<<<2048, 256, 0, stream>>>(hidden, hidden_b, SEQ * HID / 4);

    // QKV projection with fused RoPE epilogue — 1280 one-wave blocks (5/CU)
    gemm_wave<true><<<dim3(QKV_N / 64, SEQ / 64), 64, 0, stream>>>(
        hidden_b, wqkvT, b_qkv, qkv, HID, QKV_N, QKV_N, cosp, sinp);

    // MFMA flash attention: grid (q-tiles, kv-heads)
    attn_mfma_kernel<<<dim3(SEQ / 32, NKVH), 512, 0, stream>>>(qkv, sinks, attn_b);

    // output projection — 736 one-wave blocks (2.9/CU)
    gemm_wave<false><<<dim3(WO_NPAD / 64, SEQ / 64), 64, 0, stream>>>(
        attn_b, woT, b_o, (float*)d_out, ATTN_N, HID, HID, nullptr, nullptr);
}

// Round 11
// 166.232 us; speedup vs baseline: 1.1762x; 1.1762x over previous
//
#include <hip/hip_runtime.h>
#include <hip/hip_bf16.h>

#define NQH 64
#define NKVH 8
#define DH 64
#define SEQ 1024
#define HID 2880
#define QKV_N 5120   // (NQ+2*NKV)*DH
#define ATTN_N 4096  // NQ*DH
#define WIN 128
#define WO_NPAD 2944 // 23*128
#define SCALE_F 0.125f

typedef __attribute__((ext_vector_type(8))) __bf16 bf16x8;
typedef __attribute__((ext_vector_type(4))) float f32x4;

#define GLOAD_LDS16(g, l) \
    __builtin_amdgcn_global_load_lds((const __attribute__((address_space(1))) void*)(g), \
                                     (__attribute__((address_space(3))) void*)(l), 16, 0, 0)

__device__ __forceinline__ ushort f2bf(float x) {
    union { float f; unsigned int u; } c; c.f = x;
    unsigned int u = c.u;
    unsigned int r = (u + 0x7FFFu + ((u >> 16) & 1u)) >> 16;
    return (ushort)r;
}

// ---------------------------------------------------------------- convert (plain)
__global__ __launch_bounds__(256) void convert_f32_bf16(
    const float* __restrict__ in, ushort* __restrict__ out, int n4)
{
    int idx = blockIdx.x * blockDim.x + threadIdx.x;
    int stride = gridDim.x * blockDim.x;
    for (int i = idx; i < n4; i += stride) {
        float4 v = reinterpret_cast<const float4*>(in)[i];
        ushort4 o;
        o.x = f2bf(v.x); o.y = f2bf(v.y); o.z = f2bf(v.z); o.w = f2bf(v.w);
        reinterpret_cast<ushort4*>(out)[i] = o;
    }
}

// ---------------------------------------------------------------- transpose+convert
// in: [K][N] f32  ->  out: [Npad][K] bf16 (rows >= N zero-filled). K,Npad multiples of 64.
__global__ __launch_bounds__(256) void transpose_convert(
    const float* __restrict__ in, ushort* __restrict__ out, int K, int N)
{
    __shared__ ushort tile[64][80];   // row stride 160B (16B-aligned for uint4)
    const int bk = blockIdx.x * 64;   // k tile origin
    const int bn = blockIdx.y * 64;   // n tile origin
    const int tid = threadIdx.x;
    const bool inb = bn < N;          // whole tile valid or whole tile pad (N % 64 == 0)

#pragma unroll
    for (int it = 0; it < 4; ++it) {
        int r = it * 16 + (tid >> 4);         // k offset 0..63
        int c4 = (tid & 15) * 4;              // n offset
        float4 v = make_float4(0.f, 0.f, 0.f, 0.f);
        if (inb) v = *(const float4*)&in[(size_t)(bk + r) * N + bn + c4];
        tile[c4 + 0][r] = f2bf(v.x);
        tile[c4 + 1][r] = f2bf(v.y);
        tile[c4 + 2][r] = f2bf(v.z);
        tile[c4 + 3][r] = f2bf(v.w);
    }
    __syncthreads();
#pragma unroll
    for (int it = 0; it < 2; ++it) {
        int nr = it * 32 + (tid >> 3);        // n offset 0..63
        int c8 = (tid & 7) * 8;               // k offset
        uint4 v = *(const uint4*)&tile[nr][c8];
        *(uint4*)&out[(size_t)(bn + nr) * K + bk + c8] = v;
    }
}

// ---------------------------------------------------------------- GEMM 64x128, BK=32, 3-buf depth-2
// A: [M][K] bf16, BT: [Npad][K] bf16, C: [M][ldC] f32 (+bias), K % 32 == 0, K/32 >= 3.
// 256 threads = 4 waves, wave tile 32x64. THE R5-R10 SYNTHESIS:
//  - 36 KB LDS (3 bufs x 12 KB) -> 4 blocks/CU = 4 waves/SIMD (TLP to cover residual stalls)
//  - depth-2 prefetch: STAGE(t+2) then vmcnt(6) waits tile t, issued ~2 iters (~600cyc) ago
//  - counted vmcnt never 0 in steady state; lgkmcnt(0)+barrier releases buffer (T3/T4)
//  - BK=32 swizzle slot = chunk ^ ((row>>1)&3) (R8: measured 0 bank conflicts)
template<bool ROPE>
__global__ __launch_bounds__(256, 4) void gemm_p2(
    const ushort* __restrict__ A, const ushort* __restrict__ BT,
    const float* __restrict__ bias, float* __restrict__ C,
    int K, int ldC, int Nreal,
    const float* __restrict__ cosp, const float* __restrict__ sinp)
{
    __shared__ ushort Al[3 * 2048];   // 3 x 4 KB (64 x 32)
    __shared__ ushort Bl[3 * 4096];   // 3 x 8 KB (128 x 32)
    const int t = threadIdx.x;
    const int lane = t & 63;
    const int w = t >> 6;
    const int wr = w >> 1, wc = w & 1;
    const int g4 = lane >> 4;
    const int r15 = lane & 15;

    // bijective XCD swizzle (nwg % 8 == 0; 16 m-tiles)
    const int flat = blockIdx.x + gridDim.x * blockIdx.y;
    const int per = (gridDim.x * gridDim.y) >> 3;
    const int virt = (flat & 7) * per + (flat >> 3);
    const int m0 = (virt & 15) * 64;
    const int n0 = (virt >> 4) * 128;

    // ---- staging (inverse-swizzled global source, linear LDS dest) — R8-proven pattern
    // A: 64 rows x 4 chunks = 256 units (1/thread). B: 128 rows x 4 = 512 (2/thread).
    const ushort *aS, *bS0, *bS1;
    int aO, bO0, bO1;
    {
        int rowA = t >> 2;
        int chA = (t & 3) ^ ((rowA >> 1) & 3);
        aS = A + (size_t)(m0 + rowA) * K + chA * 8;
        aO = t * 8;
        int lin0 = t, lin1 = 256 + t;
        int rowB0 = lin0 >> 2, rowB1 = lin1 >> 2;
        int chB0 = (lin0 & 3) ^ ((rowB0 >> 1) & 3);
        int chB1 = (lin1 & 3) ^ ((rowB1 >> 1) & 3);
        bS0 = BT + (size_t)(n0 + rowB0) * K + chB0 * 8;
        bS1 = BT + (size_t)(n0 + rowB1) * K + chB1 * 8;
        bO0 = lin0 * 8; bO1 = lin1 * 8;
    }

#define STAGE_TILE(buf) do { \
        GLOAD_LDS16(aS,  &Al[(buf) * 2048 + aO]); \
        GLOAD_LDS16(bS0, &Bl[(buf) * 4096 + bO0]); \
        GLOAD_LDS16(bS1, &Bl[(buf) * 4096 + bO1]); \
        aS += 32; bS0 += 32; bS1 += 32; \
    } while (0)

    // ---- fragment read offsets (element units), swizzled to match staging
    int aoff[2], boff[4];
#pragma unroll
    for (int mi = 0; mi < 2; ++mi) {
        int row = wr * 32 + mi * 16 + r15;
        aoff[mi] = row * 32 + ((g4 ^ ((row >> 1) & 3)) * 8);
    }
#pragma unroll
    for (int ni = 0; ni < 4; ++ni) {
        int col = wc * 64 + ni * 16 + r15;
        boff[ni] = col * 32 + ((g4 ^ ((col >> 1) & 3)) * 8);
    }

    f32x4 acc[2][4];
#pragma unroll
    for (int mi = 0; mi < 2; ++mi)
#pragma unroll
        for (int ni = 0; ni < 4; ++ni) acc[mi][ni] = (f32x4){0.f, 0.f, 0.f, 0.f};

#define COMPUTE_TILE(buf) do { \
        const ushort* Ab = &Al[(buf) * 2048]; \
        const ushort* Bb = &Bl[(buf) * 4096]; \
        bf16x8 a0 = *(const bf16x8*)&Ab[aoff[0]]; \
        bf16x8 a1 = *(const bf16x8*)&Ab[aoff[1]]; \
        bf16x8 b0 = *(const bf16x8*)&Bb[boff[0]]; \
        bf16x8 b1 = *(const bf16x8*)&Bb[boff[1]]; \
        bf16x8 b2 = *(const bf16x8*)&Bb[boff[2]]; \
        bf16x8 b3 = *(const bf16x8*)&Bb[boff[3]]; \
        acc[0][0] = __builtin_amdgcn_mfma_f32_16x16x32_bf16(a0, b0, acc[0][0], 0, 0, 0); \
        acc[0][1] = __builtin_amdgcn_mfma_f32_16x16x32_bf16(a0, b1, acc[0][1], 0, 0, 0); \
        acc[0][2] = __builtin_amdgcn_mfma_f32_16x16x32_bf16(a0, b2, acc[0][2], 0, 0, 0); \
        acc[0][3] = __builtin_amdgcn_mfma_f32_16x16x32_bf16(a0, b3, acc[0][3], 0, 0, 0); \
        acc[1][0] = __builtin_amdgcn_mfma_f32_16x16x32_bf16(a1, b0, acc[1][0], 0, 0, 0); \
        acc[1][1] = __builtin_amdgcn_mfma_f32_16x16x32_bf16(a1, b1, acc[1][1], 0, 0, 0); \
        acc[1][2] = __builtin_amdgcn_mfma_f32_16x16x32_bf16(a1, b2, acc[1][2], 0, 0, 0); \
        acc[1][3] = __builtin_amdgcn_mfma_f32_16x16x32_bf16(a1, b3, acc[1][3], 0, 0, 0); \
    } while (0)

// one K-step: stage tile T+2 (if any), wait tile T landed (counted), compute, release buf
#define K_ITER(T, CB, SB) do { \
        if ((T) + 2 < NT) { \
            STAGE_TILE(SB); \
            asm volatile("s_waitcnt vmcnt(6)" ::: "memory"); \
        } else if ((T) + 1 < NT) { \
            asm volatile("s_waitcnt vmcnt(3)" ::: "memory"); \
        } else { \
            asm volatile("s_waitcnt vmcnt(0)" ::: "memory"); \
        } \
        __builtin_amdgcn_s_barrier(); \
        __builtin_amdgcn_sched_barrier(0); \
        COMPUTE_TILE(CB); \
        asm volatile("s_waitcnt lgkmcnt(0)" ::: "memory"); \
        __builtin_amdgcn_sched_barrier(0); \
        __builtin_amdgcn_s_barrier(); \
    } while (0)

    const int NT = K >> 5;
    STAGE_TILE(0);                 // tile 0 (3 loads in flight)
    STAGE_TILE(1);                 // tile 1 (6 in flight)
    for (int kt = 0; kt < NT; kt += 3) {
        K_ITER(kt + 0, 0, 2);
        if (kt + 1 < NT) K_ITER(kt + 1, 1, 0);
        if (kt + 2 < NT) K_ITER(kt + 2, 2, 1);
    }
#undef STAGE_TILE
#undef COMPUTE_TILE
#undef K_ITER

    // ---- epilogue: bias + optional fused RoPE in-place on acc, f32 store
    // D frag: row = (lane>>4)*4 + r (+16*mi +32*wr +m0), col = lane&15 (+16*ni +64*wc +n0)
#pragma unroll
    for (int ni = 0; ni < 4; ++ni) {
        int col = n0 + wc * 64 + ni * 16 + r15;
        float bv = (col < Nreal) ? bias[col] : 0.f;
#pragma unroll
        for (int mi = 0; mi < 2; ++mi)
#pragma unroll
            for (int r = 0; r < 4; ++r) acc[mi][ni][r] += bv;
    }
    if (ROPE) {
        const int head = (n0 + wc * 64) >> 6;   // wave-half = exactly one 64-col head
        if (head < 72) {                         // q heads 0..63, k heads 64..71; v passthrough
#pragma unroll
            for (int mi = 0; mi < 2; ++mi)
#pragma unroll
                for (int r = 0; r < 4; ++r) {
                    int q = m0 + wr * 32 + mi * 16 + g4 * 4 + r;
#pragma unroll
                    for (int dp = 0; dp < 2; ++dp) {
                        int d = dp * 16 + r15;
                        float c = cosp[q * 32 + d];
                        float s = sinp[q * 32 + d];
                        float x1 = acc[mi][dp][r];
                        float x2 = acc[mi][dp + 2][r];
                        acc[mi][dp][r]     = x1 * c - x2 * s;
                        acc[mi][dp + 2][r] = x2 * c + x1 * s;
                    }
                }
        }
    }
#pragma unroll
    for (int ni = 0; ni < 4; ++ni) {
        int col = n0 + wc * 64 + ni * 16 + r15;
        if (col < Nreal) {
#pragma unroll
            for (int mi = 0; mi < 2; ++mi) {
                int row = m0 + wr * 32 + mi * 16 + g4 * 4;
#pragma unroll
                for (int r = 0; r < 4; ++r)
                    C[(size_t)(row + r) * ldC + col] = acc[mi][ni][r];
            }
        }
    }
}

// ---------------------------------------------------------------- MFMA flash attention
__global__ __launch_bounds__(512) void attn_mfma_kernel(
    const float* __restrict__ qkv, const float* __restrict__ sinks,
    ushort* __restrict__ attn_out)
{
    __shared__ __align__(16) ushort Kl[160][72];    // [key][d], pad 64->72 (2-way free)
    __shared__ __align__(16) ushort Vt[64][168];    // [d][key], pad 160->168 (2-way free)
    __shared__ __align__(16) ushort Pl[8][32][40];  // per-wave P chunk [row][32 keys], pad->40
    const int t = threadIdx.x;
    const int w = t >> 6;
    const int l = t & 63;
    const int g4 = l >> 4;
    const int r15 = l & 15;
    const int q0 = blockIdx.x * 32;
    const int hk = blockIdx.y;
    const int kbase = q0 - 128;

    // ---- stage K [160][64] f32->bf16 and V^T [64][160]
#pragma unroll
    for (int i = 0; i < 5; ++i) {
        int idx = i * 512 + t;             // 0..2559
        int row = idx >> 4;                // 0..159
        int c4 = (idx & 15) * 4;           // 0..60
        int j = kbase + row;
        float4 kv = make_float4(0.f, 0.f, 0.f, 0.f);
        float4 vv = make_float4(0.f, 0.f, 0.f, 0.f);
        if (j >= 0) {
            kv = *(const float4*)&qkv[(size_t)j * QKV_N + 4096 + hk * 64 + c4];
            vv = *(const float4*)&qkv[(size_t)j * QKV_N + 4608 + hk * 64 + c4];
        }
        ushort4 kp;
        kp.x = f2bf(kv.x); kp.y = f2bf(kv.y); kp.z = f2bf(kv.z); kp.w = f2bf(kv.w);
        *(ushort4*)&Kl[row][c4] = kp;
        Vt[c4 + 0][row] = f2bf(vv.x);
        Vt[c4 + 1][row] = f2bf(vv.y);
        Vt[c4 + 2][row] = f2bf(vv.z);
        Vt[c4 + 3][row] = f2bf(vv.w);
    }

    // ---- Q fragments (B operand: lane supplies col = score-row = r15+16ct, k = d)
    bf16x8 qf[2][2];
#pragma unroll
    for (int ct = 0; ct < 2; ++ct) {
        int R = w * 32 + ct * 16 + r15;
        int q = q0 + (R & 31);
        int hq = hk * 8 + (R >> 5);
        const float* qb = &qkv[(size_t)q * QKV_N + hq * 64];
#pragma unroll
        for (int s = 0; s < 2; ++s) {
            float4 a = *(const float4*)&qb[s * 32 + g4 * 8];
            float4 b = *(const float4*)&qb[s * 32 + g4 * 8 + 4];
            union { ushort u[8]; bf16x8 v; } pk;
            pk.u[0] = f2bf(a.x * SCALE_F); pk.u[1] = f2bf(a.y * SCALE_F);
            pk.u[2] = f2bf(a.z * SCALE_F); pk.u[3] = f2bf(a.w * SCALE_F);
            pk.u[4] = f2bf(b.x * SCALE_F); pk.u[5] = f2bf(b.y * SCALE_F);
            pk.u[6] = f2bf(b.z * SCALE_F); pk.u[7] = f2bf(b.w * SCALE_F);
            qf[ct][s] = pk.v;
        }
    }
    __syncthreads();

    // ---- S^T = K @ Q^T : D row = key = 16kt+4g4+r, col = score-row = 16ct+r15 (+32w)
    f32x4 sc[10][2];
#pragma unroll
    for (int kt = 0; kt < 10; ++kt) {
        sc[kt][0] = (f32x4){0.f, 0.f, 0.f, 0.f};
        sc[kt][1] = (f32x4){0.f, 0.f, 0.f, 0.f};
    }
#pragma unroll
    for (int kt = 0; kt < 10; ++kt) {
#pragma unroll
        for (int s = 0; s < 2; ++s) {
            bf16x8 kf = *(const bf16x8*)&Kl[kt * 16 + r15][s * 32 + g4 * 8];
            sc[kt][0] = __builtin_amdgcn_mfma_f32_16x16x32_bf16(kf, qf[0][s], sc[kt][0], 0, 0, 0);
            sc[kt][1] = __builtin_amdgcn_mfma_f32_16x16x32_bf16(kf, qf[1][s], sc[kt][1], 0, 0, 0);
        }
    }

    // ---- masked softmax, per score-row; fold sink and 1/denom (all lane-local)
    const int minkey = 128 - q0;          // key_local >= minkey  <=>  j >= 0
#pragma unroll
    for (int ct = 0; ct < 2; ++ct) {
        int R = w * 32 + ct * 16 + r15;
        int ql = R & 31;
        float snk = sinks[hk * 8 + (R >> 5)];
#pragma unroll
        for (int kt = 0; kt < 10; ++kt)
#pragma unroll
            for (int r = 0; r < 4; ++r) {
                int key = kt * 16 + g4 * 4 + r;
                // allowed: q_local < key <= q_local+128 (window+causal), key >= minkey (j>=0)
                bool ok = (key > ql) && (key <= ql + 128) && (key >= minkey);
                if (!ok) sc[kt][ct][r] = -1e30f;
            }
        float m = snk;
#pragma unroll
        for (int kt = 0; kt < 10; ++kt)
#pragma unroll
            for (int r = 0; r < 4; ++r) m = fmaxf(m, sc[kt][ct][r]);
        m = fmaxf(m, __shfl_xor(m, 16));
        m = fmaxf(m, __shfl_xor(m, 32));
        float sum = 0.f;
#pragma unroll
        for (int kt = 0; kt < 10; ++kt)
#pragma unroll
            for (int r = 0; r < 4; ++r) {
                float p = __expf(sc[kt][ct][r] - m);
                sc[kt][ct][r] = p;
                sum += p;
            }
        sum += __shfl_xor(sum, 16);
        sum += __shfl_xor(sum, 32);
        sum += __expf(snk - m);
        float iv = 1.0f / sum;
#pragma unroll
        for (int kt = 0; kt < 10; ++kt)
#pragma unroll
            for (int r = 0; r < 4; ++r) sc[kt][ct][r] *= iv;
    }

    // ---- PV: out[row][d] = sum_key P[row][key] * V[key][d]
    f32x4 pv[2][4];
#pragma unroll
    for (int mi = 0; mi < 2; ++mi)
#pragma unroll
        for (int ni = 0; ni < 4; ++ni) pv[mi][ni] = (f32x4){0.f, 0.f, 0.f, 0.f};

#pragma unroll
    for (int s = 0; s < 5; ++s) {
#pragma unroll
        for (int ct = 0; ct < 2; ++ct)
#pragma unroll
            for (int kh = 0; kh < 2; ++kh) {
                int kt = 2 * s + kh;
                ushort4 p4;
                p4.x = f2bf(sc[kt][ct][0]);
                p4.y = f2bf(sc[kt][ct][1]);
                p4.z = f2bf(sc[kt][ct][2]);
                p4.w = f2bf(sc[kt][ct][3]);
                *(ushort4*)&Pl[w][ct * 16 + r15][kh * 16 + g4 * 4] = p4;
            }
#pragma unroll
        for (int mi = 0; mi < 2; ++mi) {
            bf16x8 pf = *(const bf16x8*)&Pl[w][mi * 16 + r15][g4 * 8];
#pragma unroll
            for (int ni = 0; ni < 4; ++ni) {
                bf16x8 vf = *(const bf16x8*)&Vt[ni * 16 + r15][s * 32 + g4 * 8];
                pv[mi][ni] = __builtin_amdgcn_mfma_f32_16x16x32_bf16(pf, vf, pv[mi][ni], 0, 0, 0);
            }
        }
    }

    // ---- write attn output (bf16): D row = 16mi+4g4+r (+32w), col = d = 16ni+r15
#pragma unroll
    for (int mi = 0; mi < 2; ++mi)
#pragma unroll
        for (int r = 0; r < 4; ++r) {
            int R = w * 32 + mi * 16 + g4 * 4 + r;
            int q = q0 + (R & 31);
            int hq = hk * 8 + (R >> 5);
            ushort* ob = &attn_out[(size_t)q * ATTN_N + hq * 64 + r15];
#pragma unroll
            for (int ni = 0; ni < 4; ++ni)
                ob[ni * 16] = f2bf(pv[mi][ni][r]);
        }
}

// ---------------------------------------------------------------- launch
extern "C" void kernel_launch(void* const* d_in, const int* in_sizes, int n_in,
                              void* d_out, int out_size, void* d_ws, size_t ws_size,
                              hipStream_t stream)
{
    const float* hidden = (const float*)d_in[0];
    const float* cosp   = (const float*)d_in[1];
    const float* sinp   = (const float*)d_in[2];
    const float* w_qkv  = (const float*)d_in[3];
    const float* b_qkv  = (const float*)d_in[4];
    const float* w_o    = (const float*)d_in[5];
    const float* b_o    = (const float*)d_in[6];
    const float* sinks  = (const float*)d_in[7];
    // d_in[8]=k_cache, d_in[9]=v_cache (zero), d_in[10]=kv_len (==0): unused.

    char* ws = (char*)d_ws;
    size_t off = 0;
    ushort* wqkvT = (ushort*)(ws + off); off += (size_t)QKV_N * HID * 2;      // [5120][2880]
    ushort* woT   = (ushort*)(ws + off); off += (size_t)WO_NPAD * ATTN_N * 2; // [2944][4096]
    float*  qkv   = (float*)(ws + off);  off += (size_t)SEQ * QKV_N * 4;
    // union region: hidden_b (gemm1 A) then attn_b (gemm2 A) — lifetimes disjoint
    ushort* hidden_b = (ushort*)(ws + off);
    ushort* attn_b   = (ushort*)(ws + off); off += (size_t)SEQ * ATTN_N * 2;
    if (off > ws_size) return;  // fail visibly rather than corrupt

    // weight transposes + hidden convert
    transpose_convert<<<dim3(HID / 64, QKV_N / 64), 256, 0, stream>>>(w_qkv, wqkvT, HID, QKV_N);
    transpose_convert<<<dim3(ATTN_N / 64, WO_NPAD / 64), 256, 0, stream>>>(w_o, woT, ATTN_N, HID);
    convert_f32_bf16<<<2048, 256, 0, stream>>>(hidden, hidden_b, SEQ * HID / 4);

    // QKV projection with fused RoPE epilogue (grid 40x16 = 640, %8==0; 4 blocks/CU)
    gemm_p2<true><<<dim3(QKV_N / 128, SEQ / 64), 256, 0, stream>>>(
        hidden_b, wqkvT, b_qkv, qkv, HID, QKV_N, QKV_N, cosp, sinp);

    // MFMA flash attention: grid (q-tiles, kv-heads)
    attn_mfma_kernel<<<dim3(SEQ / 32, NKVH), 512, 0, stream>>>(qkv, sinks, attn_b);

    // output projection (grid 23x16 = 368, %8==0)
    gemm_p2<false><<<dim3(WO_NPAD / 128, SEQ / 64), 256, 0, stream>>>(
        attn_b, woT, b_o, (float*)d_out, ATTN_N, HID, HID, nullptr, nullptr);
}

// Round 12
// 146.487 us; speedup vs baseline: 1.3347x; 1.1348x over previous
//
#include <hip/hip_runtime.h>
#include <hip/hip_bf16.h>

#define NQH 64
#define NKVH 8
#define DH 64
#define SEQ 1024
#define HID 2880
#define QKV_N 5120   // (NQ+2*NKV)*DH
#define ATTN_N 4096  // NQ*DH
#define WIN 128
#define WO_NPAD 2944 // 23*128
#define SCALE_F 0.125f

typedef __attribute__((ext_vector_type(8))) __bf16 bf16x8;
typedef __attribute__((ext_vector_type(4))) float f32x4;

#define GLOAD_LDS16(g, l) \
    __builtin_amdgcn_global_load_lds((const __attribute__((address_space(1))) void*)(g), \
                                     (__attribute__((address_space(3))) void*)(l), 16, 0, 0)

__device__ __forceinline__ ushort f2bf(float x) {
    union { float f; unsigned int u; } c; c.f = x;
    unsigned int u = c.u;
    unsigned int r = (u + 0x7FFFu + ((u >> 16) & 1u)) >> 16;
    return (ushort)r;
}

// ---------------------------------------------------------------- convert (plain)
__global__ __launch_bounds__(256) void convert_f32_bf16(
    const float* __restrict__ in, ushort* __restrict__ out, int n4)
{
    int idx = blockIdx.x * blockDim.x + threadIdx.x;
    int stride = gridDim.x * blockDim.x;
    for (int i = idx; i < n4; i += stride) {
        float4 v = reinterpret_cast<const float4*>(in)[i];
        ushort4 o;
        o.x = f2bf(v.x); o.y = f2bf(v.y); o.z = f2bf(v.z); o.w = f2bf(v.w);
        reinterpret_cast<ushort4*>(out)[i] = o;
    }
}

// ---------------------------------------------------------------- transpose+convert
// in: [K][N] f32  ->  out: [Npad][K] bf16 (rows >= N zero-filled). K,Npad multiples of 64.
__global__ __launch_bounds__(256) void transpose_convert(
    const float* __restrict__ in, ushort* __restrict__ out, int K, int N)
{
    __shared__ ushort tile[64][80];   // row stride 160B (16B-aligned for uint4)
    const int bk = blockIdx.x * 64;   // k tile origin
    const int bn = blockIdx.y * 64;   // n tile origin
    const int tid = threadIdx.x;
    const bool inb = bn < N;          // whole tile valid or whole tile pad (N % 64 == 0)

#pragma unroll
    for (int it = 0; it < 4; ++it) {
        int r = it * 16 + (tid >> 4);         // k offset 0..63
        int c4 = (tid & 15) * 4;              // n offset
        float4 v = make_float4(0.f, 0.f, 0.f, 0.f);
        if (inb) v = *(const float4*)&in[(size_t)(bk + r) * N + bn + c4];
        tile[c4 + 0][r] = f2bf(v.x);
        tile[c4 + 1][r] = f2bf(v.y);
        tile[c4 + 2][r] = f2bf(v.z);
        tile[c4 + 3][r] = f2bf(v.w);
    }
    __syncthreads();
#pragma unroll
    for (int it = 0; it < 2; ++it) {
        int nr = it * 32 + (tid >> 3);        // n offset 0..63
        int c8 = (tid & 7) * 8;               // k offset
        uint4 v = *(const uint4*)&tile[nr][c8];
        *(uint4*)&out[(size_t)(bn + nr) * K + bk + c8] = v;
    }
}

// ---------------------------------------------------------------- GEMM 128x128, 8 waves, BK=64
// A: [M][K] bf16, BT: [Npad][K] bf16, C: [M][ldC] f32 (+bias), K % 64 == 0.
// R5-R11 accounting: wall time ~= staged bytes / (~22 B/cyc/CU). 128^2 tile cuts staged
// bytes 1.5x vs 64x128 (fewer B-panel re-reads); 8 waves keep 2.5 waves/SIMD (R9's 128^2
// failed at 1 wave/SIMD). Wave grid 4(M) x 2(N), wave tile 32x64 — per-wave code identical
// to the proven R5 kernel (same frags, same rope, same 0-conflict swizzle slot=chunk^(row&7)).
// Counted vmcnt(4) dbuf: tile t's 4 loads are oldest when t+1's are in flight.
template<bool ROPE>
__global__ __launch_bounds__(512) void gemm128w8(
    const ushort* __restrict__ A, const ushort* __restrict__ BT,
    const float* __restrict__ bias, float* __restrict__ C,
    int K, int ldC, int Nreal,
    const float* __restrict__ cosp, const float* __restrict__ sinp)
{
    __shared__ ushort Al[2 * 8192];   // 2 x 16 KB (128 x 64)
    __shared__ ushort Bl[2 * 8192];   // 2 x 16 KB
    const int t = threadIdx.x;        // 0..511
    const int lane = t & 63;
    const int w = t >> 6;             // 0..7
    const int wr = w >> 1;            // 0..3 (M)
    const int wc = w & 1;             // 0..1 (N)
    const int g4 = lane >> 4;
    const int r15 = lane & 15;

    // bijective XCD swizzle (nwg % 8 == 0; 8 m-tiles)
    const int flat = blockIdx.x + gridDim.x * blockIdx.y;
    const int per = (gridDim.x * gridDim.y) >> 3;
    const int virt = (flat & 7) * per + (flat >> 3);
    const int m0 = (virt & 7) * 128;
    const int n0 = (virt >> 3) * 128;

    // ---- staging: 2 A + 2 B chunks per thread (16B each), inverse-swizzled source
    const ushort *aS0, *aS1, *bS0, *bS1;
    int dO0, dO1;
    {
        int lin0 = t, lin1 = 512 + t;
        int row0 = lin0 >> 3, row1 = lin1 >> 3;       // 0..63 / 64..127
        int ch0 = (lin0 & 7) ^ (row0 & 7);
        int ch1 = (lin1 & 7) ^ (row1 & 7);
        aS0 = A  + (size_t)(m0 + row0) * K + ch0 * 8;
        aS1 = A  + (size_t)(m0 + row1) * K + ch1 * 8;
        bS0 = BT + (size_t)(n0 + row0) * K + ch0 * 8;
        bS1 = BT + (size_t)(n0 + row1) * K + ch1 * 8;
        dO0 = lin0 * 8; dO1 = lin1 * 8;
    }

#define STAGE_TILE(buf) do { \
        GLOAD_LDS16(aS0, &Al[(buf) * 8192 + dO0]); \
        GLOAD_LDS16(aS1, &Al[(buf) * 8192 + dO1]); \
        GLOAD_LDS16(bS0, &Bl[(buf) * 8192 + dO0]); \
        GLOAD_LDS16(bS1, &Bl[(buf) * 8192 + dO1]); \
        aS0 += 64; aS1 += 64; bS0 += 64; bS1 += 64; \
    } while (0)

    // ---- fragment read offsets (element units), swizzled to match staging
    int aoff[2][2], boff[4][2];
#pragma unroll
    for (int mi = 0; mi < 2; ++mi)
#pragma unroll
        for (int ks = 0; ks < 2; ++ks) {
            int row = wr * 32 + mi * 16 + r15;
            int slot = (ks * 4 + g4) ^ (row & 7);
            aoff[mi][ks] = row * 64 + slot * 8;
        }
#pragma unroll
    for (int ni = 0; ni < 4; ++ni)
#pragma unroll
        for (int ks = 0; ks < 2; ++ks) {
            int col = wc * 64 + ni * 16 + r15;
            int slot = (ks * 4 + g4) ^ (col & 7);
            boff[ni][ks] = col * 64 + slot * 8;
        }

    f32x4 acc[2][4];
#pragma unroll
    for (int mi = 0; mi < 2; ++mi)
#pragma unroll
        for (int ni = 0; ni < 4; ++ni) acc[mi][ni] = (f32x4){0.f, 0.f, 0.f, 0.f};

#define COMPUTE_TILE(buf) do { \
        const ushort* Ab = &Al[(buf) * 8192]; \
        const ushort* Bb = &Bl[(buf) * 8192]; \
        _Pragma("unroll") \
        for (int ks = 0; ks < 2; ++ks) { \
            bf16x8 a0 = *(const bf16x8*)&Ab[aoff[0][ks]]; \
            bf16x8 a1 = *(const bf16x8*)&Ab[aoff[1][ks]]; \
            bf16x8 b0 = *(const bf16x8*)&Bb[boff[0][ks]]; \
            bf16x8 b1 = *(const bf16x8*)&Bb[boff[1][ks]]; \
            bf16x8 b2 = *(const bf16x8*)&Bb[boff[2][ks]]; \
            bf16x8 b3 = *(const bf16x8*)&Bb[boff[3][ks]]; \
            acc[0][0] = __builtin_amdgcn_mfma_f32_16x16x32_bf16(a0, b0, acc[0][0], 0, 0, 0); \
            acc[0][1] = __builtin_amdgcn_mfma_f32_16x16x32_bf16(a0, b1, acc[0][1], 0, 0, 0); \
            acc[0][2] = __builtin_amdgcn_mfma_f32_16x16x32_bf16(a0, b2, acc[0][2], 0, 0, 0); \
            acc[0][3] = __builtin_amdgcn_mfma_f32_16x16x32_bf16(a0, b3, acc[0][3], 0, 0, 0); \
            acc[1][0] = __builtin_amdgcn_mfma_f32_16x16x32_bf16(a1, b0, acc[1][0], 0, 0, 0); \
            acc[1][1] = __builtin_amdgcn_mfma_f32_16x16x32_bf16(a1, b1, acc[1][1], 0, 0, 0); \
            acc[1][2] = __builtin_amdgcn_mfma_f32_16x16x32_bf16(a1, b2, acc[1][2], 0, 0, 0); \
            acc[1][3] = __builtin_amdgcn_mfma_f32_16x16x32_bf16(a1, b3, acc[1][3], 0, 0, 0); \
        } \
    } while (0)

    const int NT = K >> 6;
    STAGE_TILE(0);                              // tile 0: 4 loads in flight
    for (int kt = 0; kt < NT; kt += 2) {
        // ---- even step: compute buf0
        if (kt + 1 < NT) {
            STAGE_TILE(1);                      // 8 in flight
            asm volatile("s_waitcnt vmcnt(4)" ::: "memory");   // tile kt landed
        } else {
            asm volatile("s_waitcnt vmcnt(0)" ::: "memory");
        }
        __builtin_amdgcn_s_barrier();
        __builtin_amdgcn_sched_barrier(0);
        COMPUTE_TILE(0);
        asm volatile("s_waitcnt lgkmcnt(0)" ::: "memory");
        __builtin_amdgcn_sched_barrier(0);
        __builtin_amdgcn_s_barrier();           // buf0 free for restage
        // ---- odd step: compute buf1
        if (kt + 1 < NT) {
            if (kt + 2 < NT) {
                STAGE_TILE(0);
                asm volatile("s_waitcnt vmcnt(4)" ::: "memory");
            } else {
                asm volatile("s_waitcnt vmcnt(0)" ::: "memory");
            }
            __builtin_amdgcn_s_barrier();
            __builtin_amdgcn_sched_barrier(0);
            COMPUTE_TILE(1);
            asm volatile("s_waitcnt lgkmcnt(0)" ::: "memory");
            __builtin_amdgcn_sched_barrier(0);
            __builtin_amdgcn_s_barrier();
        }
    }
#undef STAGE_TILE
#undef COMPUTE_TILE

    // ---- epilogue: bias + optional fused RoPE in-place on acc, f32 store
    // D frag: row = (lane>>4)*4 + r (+16*mi +32*wr +m0), col = lane&15 (+16*ni +64*wc +n0)
#pragma unroll
    for (int ni = 0; ni < 4; ++ni) {
        int col = n0 + wc * 64 + ni * 16 + r15;
        float bv = (col < Nreal) ? bias[col] : 0.f;
#pragma unroll
        for (int mi = 0; mi < 2; ++mi)
#pragma unroll
            for (int r = 0; r < 4; ++r) acc[mi][ni][r] += bv;
    }
    if (ROPE) {
        const int head = (n0 + wc * 64) >> 6;   // wave-col = exactly one 64-col head
        if (head < 72) {                         // q heads 0..63, k heads 64..71; v passthrough
#pragma unroll
            for (int mi = 0; mi < 2; ++mi)
#pragma unroll
                for (int r = 0; r < 4; ++r) {
                    int q = m0 + wr * 32 + mi * 16 + g4 * 4 + r;
#pragma unroll
                    for (int dp = 0; dp < 2; ++dp) {
                        int d = dp * 16 + r15;
                        float c = cosp[q * 32 + d];
                        float s = sinp[q * 32 + d];
                        float x1 = acc[mi][dp][r];
                        float x2 = acc[mi][dp + 2][r];
                        acc[mi][dp][r]     = x1 * c - x2 * s;
                        acc[mi][dp + 2][r] = x2 * c + x1 * s;
                    }
                }
        }
    }
#pragma unroll
    for (int ni = 0; ni < 4; ++ni) {
        int col = n0 + wc * 64 + ni * 16 + r15;
        if (col < Nreal) {
#pragma unroll
            for (int mi = 0; mi < 2; ++mi) {
                int row = m0 + wr * 32 + mi * 16 + g4 * 4;
#pragma unroll
                for (int r = 0; r < 4; ++r)
                    C[(size_t)(row + r) * ldC + col] = acc[mi][ni][r];
            }
        }
    }
}

// ---------------------------------------------------------------- MFMA flash attention
__global__ __launch_bounds__(512) void attn_mfma_kernel(
    const float* __restrict__ qkv, const float* __restrict__ sinks,
    ushort* __restrict__ attn_out)
{
    __shared__ __align__(16) ushort Kl[160][72];    // [key][d], pad 64->72 (2-way free)
    __shared__ __align__(16) ushort Vt[64][168];    // [d][key], pad 160->168 (2-way free)
    __shared__ __align__(16) ushort Pl[8][32][40];  // per-wave P chunk [row][32 keys], pad->40
    const int t = threadIdx.x;
    const int w = t >> 6;
    const int l = t & 63;
    const int g4 = l >> 4;
    const int r15 = l & 15;
    const int q0 = blockIdx.x * 32;
    const int hk = blockIdx.y;
    const int kbase = q0 - 128;

    // ---- stage K [160][64] f32->bf16 and V^T [64][160]
#pragma unroll
    for (int i = 0; i < 5; ++i) {
        int idx = i * 512 + t;             // 0..2559
        int row = idx >> 4;                // 0..159
        int c4 = (idx & 15) * 4;           // 0..60
        int j = kbase + row;
        float4 kv = make_float4(0.f, 0.f, 0.f, 0.f);
        float4 vv = make_float4(0.f, 0.f, 0.f, 0.f);
        if (j >= 0) {
            kv = *(const float4*)&qkv[(size_t)j * QKV_N + 4096 + hk * 64 + c4];
            vv = *(const float4*)&qkv[(size_t)j * QKV_N + 4608 + hk * 64 + c4];
        }
        ushort4 kp;
        kp.x = f2bf(kv.x); kp.y = f2bf(kv.y); kp.z = f2bf(kv.z); kp.w = f2bf(kv.w);
        *(ushort4*)&Kl[row][c4] = kp;
        Vt[c4 + 0][row] = f2bf(vv.x);
        Vt[c4 + 1][row] = f2bf(vv.y);
        Vt[c4 + 2][row] = f2bf(vv.z);
        Vt[c4 + 3][row] = f2bf(vv.w);
    }

    // ---- Q fragments (B operand: lane supplies col = score-row = r15+16ct, k = d)
    bf16x8 qf[2][2];
#pragma unroll
    for (int ct = 0; ct < 2; ++ct) {
        int R = w * 32 + ct * 16 + r15;
        int q = q0 + (R & 31);
        int hq = hk * 8 + (R >> 5);
        const float* qb = &qkv[(size_t)q * QKV_N + hq * 64];
#pragma unroll
        for (int s = 0; s < 2; ++s) {
            float4 a = *(const float4*)&qb[s * 32 + g4 * 8];
            float4 b = *(const float4*)&qb[s * 32 + g4 * 8 + 4];
            union { ushort u[8]; bf16x8 v; } pk;
            pk.u[0] = f2bf(a.x * SCALE_F); pk.u[1] = f2bf(a.y * SCALE_F);
            pk.u[2] = f2bf(a.z * SCALE_F); pk.u[3] = f2bf(a.w * SCALE_F);
            pk.u[4] = f2bf(b.x * SCALE_F); pk.u[5] = f2bf(b.y * SCALE_F);
            pk.u[6] = f2bf(b.z * SCALE_F); pk.u[7] = f2bf(b.w * SCALE_F);
            qf[ct][s] = pk.v;
        }
    }
    __syncthreads();

    // ---- S^T = K @ Q^T : D row = key = 16kt+4g4+r, col = score-row = 16ct+r15 (+32w)
    f32x4 sc[10][2];
#pragma unroll
    for (int kt = 0; kt < 10; ++kt) {
        sc[kt][0] = (f32x4){0.f, 0.f, 0.f, 0.f};
        sc[kt][1] = (f32x4){0.f, 0.f, 0.f, 0.f};
    }
#pragma unroll
    for (int kt = 0; kt < 10; ++kt) {
#pragma unroll
        for (int s = 0; s < 2; ++s) {
            bf16x8 kf = *(const bf16x8*)&Kl[kt * 16 + r15][s * 32 + g4 * 8];
            sc[kt][0] = __builtin_amdgcn_mfma_f32_16x16x32_bf16(kf, qf[0][s], sc[kt][0], 0, 0, 0);
            sc[kt][1] = __builtin_amdgcn_mfma_f32_16x16x32_bf16(kf, qf[1][s], sc[kt][1], 0, 0, 0);
        }
    }

    // ---- masked softmax, per score-row; fold sink and 1/denom (all lane-local)
    const int minkey = 128 - q0;          // key_local >= minkey  <=>  j >= 0
#pragma unroll
    for (int ct = 0; ct < 2; ++ct) {
        int R = w * 32 + ct * 16 + r15;
        int ql = R & 31;
        float snk = sinks[hk * 8 + (R >> 5)];
#pragma unroll
        for (int kt = 0; kt < 10; ++kt)
#pragma unroll
            for (int r = 0; r < 4; ++r) {
                int key = kt * 16 + g4 * 4 + r;
                // allowed: q_local < key <= q_local+128 (window+causal), key >= minkey (j>=0)
                bool ok = (key > ql) && (key <= ql + 128) && (key >= minkey);
                if (!ok) sc[kt][ct][r] = -1e30f;
            }
        float m = snk;
#pragma unroll
        for (int kt = 0; kt < 10; ++kt)
#pragma unroll
            for (int r = 0; r < 4; ++r) m = fmaxf(m, sc[kt][ct][r]);
        m = fmaxf(m, __shfl_xor(m, 16));
        m = fmaxf(m, __shfl_xor(m, 32));
        float sum = 0.f;
#pragma unroll
        for (int kt = 0; kt < 10; ++kt)
#pragma unroll
            for (int r = 0; r < 4; ++r) {
                float p = __expf(sc[kt][ct][r] - m);
                sc[kt][ct][r] = p;
                sum += p;
            }
        sum += __shfl_xor(sum, 16);
        sum += __shfl_xor(sum, 32);
        sum += __expf(snk - m);
        float iv = 1.0f / sum;
#pragma unroll
        for (int kt = 0; kt < 10; ++kt)
#pragma unroll
            for (int r = 0; r < 4; ++r) sc[kt][ct][r] *= iv;
    }

    // ---- PV: out[row][d] = sum_key P[row][key] * V[key][d]
    f32x4 pv[2][4];
#pragma unroll
    for (int mi = 0; mi < 2; ++mi)
#pragma unroll
        for (int ni = 0; ni < 4; ++ni) pv[mi][ni] = (f32x4){0.f, 0.f, 0.f, 0.f};

#pragma unroll
    for (int s = 0; s < 5; ++s) {
#pragma unroll
        for (int ct = 0; ct < 2; ++ct)
#pragma unroll
            for (int kh = 0; kh < 2; ++kh) {
                int kt = 2 * s + kh;
                ushort4 p4;
                p4.x = f2bf(sc[kt][ct][0]);
                p4.y = f2bf(sc[kt][ct][1]);
                p4.z = f2bf(sc[kt][ct][2]);
                p4.w = f2bf(sc[kt][ct][3]);
                *(ushort4*)&Pl[w][ct * 16 + r15][kh * 16 + g4 * 4] = p4;
            }
#pragma unroll
        for (int mi = 0; mi < 2; ++mi) {
            bf16x8 pf = *(const bf16x8*)&Pl[w][mi * 16 + r15][g4 * 8];
#pragma unroll
            for (int ni = 0; ni < 4; ++ni) {
                bf16x8 vf = *(const bf16x8*)&Vt[ni * 16 + r15][s * 32 + g4 * 8];
                pv[mi][ni] = __builtin_amdgcn_mfma_f32_16x16x32_bf16(pf, vf, pv[mi][ni], 0, 0, 0);
            }
        }
    }

    // ---- write attn output (bf16): D row = 16mi+4g4+r (+32w), col = d = 16ni+r15
#pragma unroll
    for (int mi = 0; mi < 2; ++mi)
#pragma unroll
        for (int r = 0; r < 4; ++r) {
            int R = w * 32 + mi * 16 + g4 * 4 + r;
            int q = q0 + (R & 31);
            int hq = hk * 8 + (R >> 5);
            ushort* ob = &attn_out[(size_t)q * ATTN_N + hq * 64 + r15];
#pragma unroll
            for (int ni = 0; ni < 4; ++ni)
                ob[ni * 16] = f2bf(pv[mi][ni][r]);
        }
}

// ---------------------------------------------------------------- launch
extern "C" void kernel_launch(void* const* d_in, const int* in_sizes, int n_in,
                              void* d_out, int out_size, void* d_ws, size_t ws_size,
                              hipStream_t stream)
{
    const float* hidden = (const float*)d_in[0];
    const float* cosp   = (const float*)d_in[1];
    const float* sinp   = (const float*)d_in[2];
    const float* w_qkv  = (const float*)d_in[3];
    const float* b_qkv  = (const float*)d_in[4];
    const float* w_o    = (const float*)d_in[5];
    const float* b_o    = (const float*)d_in[6];
    const float* sinks  = (const float*)d_in[7];
    // d_in[8]=k_cache, d_in[9]=v_cache (zero), d_in[10]=kv_len (==0): unused.

    char* ws = (char*)d_ws;
    size_t off = 0;
    ushort* wqkvT = (ushort*)(ws + off); off += (size_t)QKV_N * HID * 2;      // [5120][2880]
    ushort* woT   = (ushort*)(ws + off); off += (size_t)WO_NPAD * ATTN_N * 2; // [2944][4096]
    float*  qkv   = (float*)(ws + off);  off += (size_t)SEQ * QKV_N * 4;
    // union region: hidden_b (gemm1 A) then attn_b (gemm2 A) — lifetimes disjoint
    ushort* hidden_b = (ushort*)(ws + off);
    ushort* attn_b   = (ushort*)(ws + off); off += (size_t)SEQ * ATTN_N * 2;
    if (off > ws_size) return;  // fail visibly rather than corrupt

    // weight transposes + hidden convert
    transpose_convert<<<dim3(HID / 64, QKV_N / 64), 256, 0, stream>>>(w_qkv, wqkvT, HID, QKV_N);
    transpose_convert<<<dim3(ATTN_N / 64, WO_NPAD / 64), 256, 0, stream>>>(w_o, woT, ATTN_N, HID);
    convert_f32_bf16<<<2048, 256, 0, stream>>>(hidden, hidden_b, SEQ * HID / 4);

    // QKV projection with fused RoPE epilogue (grid 40x8 = 320 blocks x 8 waves)
    gemm128w8<true><<<dim3(QKV_N / 128, SEQ / 128), 512, 0, stream>>>(
        hidden_b, wqkvT, b_qkv, qkv, HID, QKV_N, QKV_N, cosp, sinp);

    // MFMA flash attention: grid (q-tiles, kv-heads)
    attn_mfma_kernel<<<dim3(SEQ / 32, NKVH), 512, 0, stream>>>(qkv, sinks, attn_b);

    // output projection (grid 23x8 = 184 blocks x 8 waves)
    gemm128w8<false><<<dim3(WO_NPAD / 128, SEQ / 128), 512, 0, stream>>>(
        attn_b, woT, b_o, (float*)d_out, ATTN_N, HID, HID, nullptr, nullptr);
}

// Round 13
// 140.770 us; speedup vs baseline: 1.3889x; 1.0406x over previous
//
#include <hip/hip_runtime.h>
#include <hip/hip_bf16.h>

#define NQH 64
#define NKVH 8
#define DH 64
#define SEQ 1024
#define HID 2880
#define QKV_N 5120   // (NQ+2*NKV)*DH
#define ATTN_N 4096  // NQ*DH
#define WIN 128
#define WO_NPAD 3072 // 32*96 (zero-padded rows 2880..3071)
#define SCALE_F 0.125f

typedef __attribute__((ext_vector_type(8))) __bf16 bf16x8;
typedef __attribute__((ext_vector_type(4))) float f32x4;

#define GLOAD_LDS16(g, l) \
    __builtin_amdgcn_global_load_lds((const __attribute__((address_space(1))) void*)(g), \
                                     (__attribute__((address_space(3))) void*)(l), 16, 0, 0)

__device__ __forceinline__ ushort f2bf(float x) {
    union { float f; unsigned int u; } c; c.f = x;
    unsigned int u = c.u;
    unsigned int r = (u + 0x7FFFu + ((u >> 16) & 1u)) >> 16;
    return (ushort)r;
}

// ---------------------------------------------------------------- convert (plain)
__global__ __launch_bounds__(256) void convert_f32_bf16(
    const float* __restrict__ in, ushort* __restrict__ out, int n4)
{
    int idx = blockIdx.x * blockDim.x + threadIdx.x;
    int stride = gridDim.x * blockDim.x;
    for (int i = idx; i < n4; i += stride) {
        float4 v = reinterpret_cast<const float4*>(in)[i];
        ushort4 o;
        o.x = f2bf(v.x); o.y = f2bf(v.y); o.z = f2bf(v.z); o.w = f2bf(v.w);
        reinterpret_cast<ushort4*>(out)[i] = o;
    }
}

// ---------------------------------------------------------------- transpose+convert
// in: [K][N] f32  ->  out: [Npad][K] bf16 (rows >= N zero-filled). K,Npad multiples of 64.
__global__ __launch_bounds__(256) void transpose_convert(
    const float* __restrict__ in, ushort* __restrict__ out, int K, int N)
{
    __shared__ ushort tile[64][80];   // row stride 160B (16B-aligned for uint4)
    const int bk = blockIdx.x * 64;   // k tile origin
    const int bn = blockIdx.y * 64;   // n tile origin
    const int tid = threadIdx.x;
    const bool inb = bn < N;          // whole tile valid or whole tile pad (N % 64 == 0)

#pragma unroll
    for (int it = 0; it < 4; ++it) {
        int r = it * 16 + (tid >> 4);         // k offset 0..63
        int c4 = (tid & 15) * 4;              // n offset
        float4 v = make_float4(0.f, 0.f, 0.f, 0.f);
        if (inb) v = *(const float4*)&in[(size_t)(bk + r) * N + bn + c4];
        tile[c4 + 0][r] = f2bf(v.x);
        tile[c4 + 1][r] = f2bf(v.y);
        tile[c4 + 2][r] = f2bf(v.z);
        tile[c4 + 3][r] = f2bf(v.w);
    }
    __syncthreads();
#pragma unroll
    for (int it = 0; it < 2; ++it) {
        int nr = it * 32 + (tid >> 3);        // n offset 0..63
        int c8 = (tid & 7) * 8;               // k offset
        uint4 v = *(const uint4*)&tile[nr][c8];
        *(uint4*)&out[(size_t)(bn + nr) * K + bk + c8] = v;
    }
}

// ---------------------------------------------------------------- balanced-grid GEMM, BK=64
// A: [M][K] bf16, BT: [Npad][K] bf16, C: [M][ldC] f32 (+bias), K % 64 == 0.
// R12 finding: per-CU staging rate is ~22 B/cyc (universal: ours, m97, HK all ~22) and
// needs >=2 resident blocks/CU; wall = heavy-CU staged bytes / 22. So: grid EXACTLY 512
// (2/CU, all CUs identical) with minimum-perimeter tiles:
//   gemm1 128x80 (64x8 grid), gemm2 64x96 (32x16 grid, Npad 3072).
// 512 threads = 8 waves, wave grid WAVES_M x WAVES_N, wave tile (BM/WAVES_M) x (BN/WAVES_N).
// R5 dbuf sync structure (counted variants measured equivalent); verified swizzle family
// slot = chunk ^ (row&7) (0 conflicts measured).
template<int BM, int BN, int WAVES_N>
__global__ __launch_bounds__(512) void gemm_bal(
    const ushort* __restrict__ A, const ushort* __restrict__ BT,
    const float* __restrict__ bias, float* __restrict__ C,
    int K, int ldC, int Nreal)
{
    constexpr int WAVES_M = 8 / WAVES_N;
    constexpr int WM = BM / WAVES_M;
    constexpr int WN = BN / WAVES_N;
    constexpr int MR = WM / 16;
    constexpr int NR = WN / 16;
    constexpr int ASZ = BM * 64;          // elements per buffer
    constexpr int BSZ = BN * 64;
    constexpr int ACH = BM * 8;           // 16B chunks in A tile
    constexpr int TOTCH = (BM + BN) * 8;
    constexpr int NLOAD = (TOTCH + 511) / 512;

    __shared__ ushort Al[2 * ASZ];
    __shared__ ushort Bl[2 * BSZ];

    const int t = threadIdx.x;
    const int lane = t & 63;
    const int w = t >> 6;
    const int wr = w / WAVES_N;
    const int wc = w % WAVES_N;
    const int g4 = lane >> 4;
    const int r15 = lane & 15;

    // bijective XCD swizzle (nwg = 512, % 8 == 0); within an XCD, n-tiles walk fastest
    // so the A panel stays hot in that XCD's L2.
    const int nx = gridDim.x;
    const int flat = blockIdx.x + nx * blockIdx.y;
    const int per = (nx * gridDim.y) >> 3;
    const int virt = (flat & 7) * per + (flat >> 3);
    const int n0 = (virt % nx) * BN;
    const int m0 = (virt / nx) * BM;

    // ---- staging tables (inverse-swizzled global source, linear LDS dest)
    const ushort* src[NLOAD];
    ushort* d0[NLOAD];
    ushort* d1[NLOAD];
#pragma unroll
    for (int i = 0; i < NLOAD; ++i) {
        int lin = i * 512 + t;
        src[i] = nullptr; d0[i] = nullptr; d1[i] = nullptr;
        if (lin < ACH) {
            int row = lin >> 3, ch = (lin & 7) ^ (row & 7);
            src[i] = A + (size_t)(m0 + row) * K + ch * 8;
            d0[i] = &Al[lin * 8];
            d1[i] = &Al[ASZ + lin * 8];
        } else if (lin < TOTCH) {
            int l2 = lin - ACH;
            int row = l2 >> 3, ch = (l2 & 7) ^ (row & 7);
            src[i] = BT + (size_t)(n0 + row) * K + ch * 8;
            d0[i] = &Bl[l2 * 8];
            d1[i] = &Bl[BSZ + l2 * 8];
        }
    }

#define STAGE_TILE(buf) do { \
        _Pragma("unroll") \
        for (int i = 0; i < NLOAD; ++i) \
            if (src[i]) { \
                GLOAD_LDS16(src[i], (buf) ? d1[i] : d0[i]); \
                src[i] += 64; \
            } \
    } while (0)

    // ---- fragment read offsets (element units), swizzled to match staging
    int aoff[MR][2], boff[NR][2];
#pragma unroll
    for (int mi = 0; mi < MR; ++mi)
#pragma unroll
        for (int ks = 0; ks < 2; ++ks) {
            int row = wr * WM + mi * 16 + r15;
            aoff[mi][ks] = row * 64 + (((ks * 4 + g4) ^ (row & 7)) * 8);
        }
#pragma unroll
    for (int ni = 0; ni < NR; ++ni)
#pragma unroll
        for (int ks = 0; ks < 2; ++ks) {
            int col = wc * WN + ni * 16 + r15;
            boff[ni][ks] = col * 64 + (((ks * 4 + g4) ^ (col & 7)) * 8);
        }

    f32x4 acc[MR][NR];
#pragma unroll
    for (int mi = 0; mi < MR; ++mi)
#pragma unroll
        for (int ni = 0; ni < NR; ++ni) acc[mi][ni] = (f32x4){0.f, 0.f, 0.f, 0.f};

#define COMPUTE_TILE(buf) do { \
        const ushort* Ab = &Al[(buf) * ASZ]; \
        const ushort* Bb = &Bl[(buf) * BSZ]; \
        _Pragma("unroll") \
        for (int ks = 0; ks < 2; ++ks) { \
            bf16x8 af[MR], bfr[NR]; \
            _Pragma("unroll") \
            for (int mi = 0; mi < MR; ++mi) af[mi] = *(const bf16x8*)&Ab[aoff[mi][ks]]; \
            _Pragma("unroll") \
            for (int ni = 0; ni < NR; ++ni) bfr[ni] = *(const bf16x8*)&Bb[boff[ni][ks]]; \
            _Pragma("unroll") \
            for (int mi = 0; mi < MR; ++mi) \
                _Pragma("unroll") \
                for (int ni = 0; ni < NR; ++ni) \
                    acc[mi][ni] = __builtin_amdgcn_mfma_f32_16x16x32_bf16(af[mi], bfr[ni], acc[mi][ni], 0, 0, 0); \
        } \
    } while (0)

    const int NT = K >> 6;
    STAGE_TILE(0);
    __syncthreads();                            // tile 0 ready
    for (int kt = 0; kt < NT; kt += 2) {
        if (kt + 1 < NT) STAGE_TILE(1);         // prefetch next before compute
        COMPUTE_TILE(0);
        __syncthreads();
        if (kt + 1 < NT) {
            if (kt + 2 < NT) STAGE_TILE(0);
            COMPUTE_TILE(1);
            __syncthreads();
        }
    }
#undef STAGE_TILE
#undef COMPUTE_TILE

    // ---- epilogue: bias, f32 store (no rope here — rope fused into attention load)
    // D frag: row = g4*4 + r (+16*mi +WM*wr +m0), col = r15 (+16*ni +WN*wc +n0)
#pragma unroll
    for (int ni = 0; ni < NR; ++ni) {
        int col = n0 + wc * WN + ni * 16 + r15;
        if (col < Nreal) {
            float bv = bias[col];
#pragma unroll
            for (int mi = 0; mi < MR; ++mi) {
                int row = m0 + wr * WM + mi * 16 + g4 * 4;
#pragma unroll
                for (int r = 0; r < 4; ++r)
                    C[(size_t)(row + r) * ldC + col] = acc[mi][ni][r] + bv;
            }
        }
    }
}

// ---------------------------------------------------------------- MFMA flash attention (+fused RoPE)
// qkv holds RAW (bias-added, un-roped) q,k,v. RoPE applied here in f32 during bf16 convert:
//   d<32:  x' = x*cos[d] - y*sin[d]        (y = elem at d+32)
//   d>=32: x' = x*cos[d-32] + y*sin[d-32]  (y = elem at d-32)
__global__ __launch_bounds__(512) void attn_mfma_kernel(
    const float* __restrict__ qkv, const float* __restrict__ sinks,
    const float* __restrict__ cosp, const float* __restrict__ sinp,
    ushort* __restrict__ attn_out)
{
    __shared__ __align__(16) ushort Kl[160][72];    // [key][d], pad 64->72 (2-way free)
    __shared__ __align__(16) ushort Vt[64][168];    // [d][key], pad 160->168 (2-way free)
    __shared__ __align__(16) ushort Pl[8][32][40];  // per-wave P chunk [row][32 keys], pad->40
    const int t = threadIdx.x;
    const int w = t >> 6;
    const int l = t & 63;
    const int g4 = l >> 4;
    const int r15 = l & 15;
    const int q0 = blockIdx.x * 32;
    const int hk = blockIdx.y;
    const int kbase = q0 - 128;

    // ---- stage K (rope'd) [160][64] f32->bf16 and V^T [64][160]
#pragma unroll
    for (int i = 0; i < 5; ++i) {
        int idx = i * 512 + t;             // 0..2559
        int row = idx >> 4;                // 0..159
        int c4 = (idx & 15) * 4;           // 0..60
        int j = kbase + row;
        float4 kr = make_float4(0.f, 0.f, 0.f, 0.f);
        float4 vv = make_float4(0.f, 0.f, 0.f, 0.f);
        if (j >= 0) {
            const float* kb = &qkv[(size_t)j * QKV_N + 4096 + hk * 64];
            float4 kx = *(const float4*)&kb[c4];
            float4 ky = *(const float4*)&kb[c4 ^ 32];
            float4 cs = *(const float4*)&cosp[j * 32 + (c4 & 31)];
            float4 sn = *(const float4*)&sinp[j * 32 + (c4 & 31)];
            if (c4 < 32) {
                kr.x = kx.x * cs.x - ky.x * sn.x; kr.y = kx.y * cs.y - ky.y * sn.y;
                kr.z = kx.z * cs.z - ky.z * sn.z; kr.w = kx.w * cs.w - ky.w * sn.w;
            } else {
                kr.x = kx.x * cs.x + ky.x * sn.x; kr.y = kx.y * cs.y + ky.y * sn.y;
                kr.z = kx.z * cs.z + ky.z * sn.z; kr.w = kx.w * cs.w + ky.w * sn.w;
            }
            vv = *(const float4*)&qkv[(size_t)j * QKV_N + 4608 + hk * 64 + c4];
        }
        ushort4 kp;
        kp.x = f2bf(kr.x); kp.y = f2bf(kr.y); kp.z = f2bf(kr.z); kp.w = f2bf(kr.w);
        *(ushort4*)&Kl[row][c4] = kp;
        Vt[c4 + 0][row] = f2bf(vv.x);
        Vt[c4 + 1][row] = f2bf(vv.y);
        Vt[c4 + 2][row] = f2bf(vv.z);
        Vt[c4 + 3][row] = f2bf(vv.w);
    }

    // ---- Q fragments, rope'd (B operand: lane supplies col = score-row = r15+16ct, k = d)
    bf16x8 qf[2][2];
#pragma unroll
    for (int ct = 0; ct < 2; ++ct) {
        int R = w * 32 + ct * 16 + r15;
        int q = q0 + (R & 31);
        int hq = hk * 8 + (R >> 5);
        const float* qb = &qkv[(size_t)q * QKV_N + hq * 64];
        int d8 = g4 * 8;                       // 0,8,16,24 (first-half base)
        float4 a0 = *(const float4*)&qb[d8];          // s=0 lo
        float4 b0 = *(const float4*)&qb[d8 + 4];      // s=0 hi
        float4 a1 = *(const float4*)&qb[32 + d8];     // s=1 lo
        float4 b1 = *(const float4*)&qb[32 + d8 + 4]; // s=1 hi
        float4 c0 = *(const float4*)&cosp[q * 32 + d8];
        float4 c1 = *(const float4*)&cosp[q * 32 + d8 + 4];
        float4 s0 = *(const float4*)&sinp[q * 32 + d8];
        float4 s1 = *(const float4*)&sinp[q * 32 + d8 + 4];
        union { ushort u[8]; bf16x8 v; } p0, p1;
        p0.u[0] = f2bf((a0.x * c0.x - a1.x * s0.x) * SCALE_F);
        p0.u[1] = f2bf((a0.y * c0.y - a1.y * s0.y) * SCALE_F);
        p0.u[2] = f2bf((a0.z * c0.z - a1.z * s0.z) * SCALE_F);
        p0.u[3] = f2bf((a0.w * c0.w - a1.w * s0.w) * SCALE_F);
        p0.u[4] = f2bf((b0.x * c1.x - b1.x * s1.x) * SCALE_F);
        p0.u[5] = f2bf((b0.y * c1.y - b1.y * s1.y) * SCALE_F);
        p0.u[6] = f2bf((b0.z * c1.z - b1.z * s1.z) * SCALE_F);
        p0.u[7] = f2bf((b0.w * c1.w - b1.w * s1.w) * SCALE_F);
        p1.u[0] = f2bf((a1.x * c0.x + a0.x * s0.x) * SCALE_F);
        p1.u[1] = f2bf((a1.y * c0.y + a0.y * s0.y) * SCALE_F);
        p1.u[2] = f2bf((a1.z * c0.z + a0.z * s0.z) * SCALE_F);
        p1.u[3] = f2bf((a1.w * c0.w + a0.w * s0.w) * SCALE_F);
        p1.u[4] = f2bf((b1.x * c1.x + b0.x * s1.x) * SCALE_F);
        p1.u[5] = f2bf((b1.y * c1.y + b0.y * s1.y) * SCALE_F);
        p1.u[6] = f2bf((b1.z * c1.z + b0.z * s1.z) * SCALE_F);
        p1.u[7] = f2bf((b1.w * c1.w + b0.w * s1.w) * SCALE_F);
        qf[ct][0] = p0.v;
        qf[ct][1] = p1.v;
    }
    __syncthreads();

    // ---- S^T = K @ Q^T : D row = key = 16kt+4g4+r, col = score-row = 16ct+r15 (+32w)
    f32x4 sc[10][2];
#pragma unroll
    for (int kt = 0; kt < 10; ++kt) {
        sc[kt][0] = (f32x4){0.f, 0.f, 0.f, 0.f};
        sc[kt][1] = (f32x4){0.f, 0.f, 0.f, 0.f};
    }
#pragma unroll
    for (int kt = 0; kt < 10; ++kt) {
#pragma unroll
        for (int s = 0; s < 2; ++s) {
            bf16x8 kf = *(const bf16x8*)&Kl[kt * 16 + r15][s * 32 + g4 * 8];
            sc[kt][0] = __builtin_amdgcn_mfma_f32_16x16x32_bf16(kf, qf[0][s], sc[kt][0], 0, 0, 0);
            sc[kt][1] = __builtin_amdgcn_mfma_f32_16x16x32_bf16(kf, qf[1][s], sc[kt][1], 0, 0, 0);
        }
    }

    // ---- masked softmax, per score-row; fold sink and 1/denom (all lane-local)
    const int minkey = 128 - q0;          // key_local >= minkey  <=>  j >= 0
#pragma unroll
    for (int ct = 0; ct < 2; ++ct) {
        int R = w * 32 + ct * 16 + r15;
        int ql = R & 31;
        float snk = sinks[hk * 8 + (R >> 5)];
#pragma unroll
        for (int kt = 0; kt < 10; ++kt)
#pragma unroll
            for (int r = 0; r < 4; ++r) {
                int key = kt * 16 + g4 * 4 + r;
                // allowed: q_local < key <= q_local+128 (window+causal), key >= minkey (j>=0)
                bool ok = (key > ql) && (key <= ql + 128) && (key >= minkey);
                if (!ok) sc[kt][ct][r] = -1e30f;
            }
        float m = snk;
#pragma unroll
        for (int kt = 0; kt < 10; ++kt)
#pragma unroll
            for (int r = 0; r < 4; ++r) m = fmaxf(m, sc[kt][ct][r]);
        m = fmaxf(m, __shfl_xor(m, 16));
        m = fmaxf(m, __shfl_xor(m, 32));
        float sum = 0.f;
#pragma unroll
        for (int kt = 0; kt < 10; ++kt)
#pragma unroll
            for (int r = 0; r < 4; ++r) {
                float p = __expf(sc[kt][ct][r] - m);
                sc[kt][ct][r] = p;
                sum += p;
            }
        sum += __shfl_xor(sum, 16);
        sum += __shfl_xor(sum, 32);
        sum += __expf(snk - m);
        float iv = 1.0f / sum;
#pragma unroll
        for (int kt = 0; kt < 10; ++kt)
#pragma unroll
            for (int r = 0; r < 4; ++r) sc[kt][ct][r] *= iv;
    }

    // ---- PV: out[row][d] = sum_key P[row][key] * V[key][d]
    f32x4 pv[2][4];
#pragma unroll
    for (int mi = 0; mi < 2; ++mi)
#pragma unroll
        for (int ni = 0; ni < 4; ++ni) pv[mi][ni] = (f32x4){0.f, 0.f, 0.f, 0.f};

#pragma unroll
    for (int s = 0; s < 5; ++s) {
#pragma unroll
        for (int ct = 0; ct < 2; ++ct)
#pragma unroll
            for (int kh = 0; kh < 2; ++kh) {
                int kt = 2 * s + kh;
                ushort4 p4;
                p4.x = f2bf(sc[kt][ct][0]);
                p4.y = f2bf(sc[kt][ct][1]);
                p4.z = f2bf(sc[kt][ct][2]);
                p4.w = f2bf(sc[kt][ct][3]);
                *(ushort4*)&Pl[w][ct * 16 + r15][kh * 16 + g4 * 4] = p4;
            }
#pragma unroll
        for (int mi = 0; mi < 2; ++mi) {
            bf16x8 pf = *(const bf16x8*)&Pl[w][mi * 16 + r15][g4 * 8];
#pragma unroll
            for (int ni = 0; ni < 4; ++ni) {
                bf16x8 vf = *(const bf16x8*)&Vt[ni * 16 + r15][s * 32 + g4 * 8];
                pv[mi][ni] = __builtin_amdgcn_mfma_f32_16x16x32_bf16(pf, vf, pv[mi][ni], 0, 0, 0);
            }
        }
    }

    // ---- write attn output (bf16): D row = 16mi+4g4+r (+32w), col = d = 16ni+r15
#pragma unroll
    for (int mi = 0; mi < 2; ++mi)
#pragma unroll
        for (int r = 0; r < 4; ++r) {
            int R = w * 32 + mi * 16 + g4 * 4 + r;
            int q = q0 + (R & 31);
            int hq = hk * 8 + (R >> 5);
            ushort* ob = &attn_out[(size_t)q * ATTN_N + hq * 64 + r15];
#pragma unroll
            for (int ni = 0; ni < 4; ++ni)
                ob[ni * 16] = f2bf(pv[mi][ni][r]);
        }
}

// ---------------------------------------------------------------- launch
extern "C" void kernel_launch(void* const* d_in, const int* in_sizes, int n_in,
                              void* d_out, int out_size, void* d_ws, size_t ws_size,
                              hipStream_t stream)
{
    const float* hidden = (const float*)d_in[0];
    const float* cosp   = (const float*)d_in[1];
    const float* sinp   = (const float*)d_in[2];
    const float* w_qkv  = (const float*)d_in[3];
    const float* b_qkv  = (const float*)d_in[4];
    const float* w_o    = (const float*)d_in[5];
    const float* b_o    = (const float*)d_in[6];
    const float* sinks  = (const float*)d_in[7];
    // d_in[8]=k_cache, d_in[9]=v_cache (zero), d_in[10]=kv_len (==0): unused.

    char* ws = (char*)d_ws;
    size_t off = 0;
    ushort* wqkvT = (ushort*)(ws + off); off += (size_t)QKV_N * HID * 2;      // [5120][2880]
    ushort* woT   = (ushort*)(ws + off); off += (size_t)WO_NPAD * ATTN_N * 2; // [3072][4096]
    float*  qkv   = (float*)(ws + off);  off += (size_t)SEQ * QKV_N * 4;
    // union region: hidden_b (gemm1 A) then attn_b (gemm2 A) — lifetimes disjoint
    ushort* hidden_b = (ushort*)(ws + off);
    ushort* attn_b   = (ushort*)(ws + off); off += (size_t)SEQ * ATTN_N * 2;
    if (off > ws_size) return;  // fail visibly rather than corrupt

    // weight transposes + hidden convert
    transpose_convert<<<dim3(HID / 64, QKV_N / 64), 256, 0, stream>>>(w_qkv, wqkvT, HID, QKV_N);
    transpose_convert<<<dim3(ATTN_N / 64, WO_NPAD / 64), 256, 0, stream>>>(w_o, woT, ATTN_N, HID);
    convert_f32_bf16<<<2048, 256, 0, stream>>>(hidden, hidden_b, SEQ * HID / 4);

    // QKV projection, raw+bias (rope deferred to attention). Tile 128x80, grid 64x8 = 512.
    gemm_bal<128, 80, 1><<<dim3(QKV_N / 80, SEQ / 128), 512, 0, stream>>>(
        hidden_b, wqkvT, b_qkv, qkv, HID, QKV_N, QKV_N);

    // MFMA flash attention with fused RoPE on Q and K
    attn_mfma_kernel<<<dim3(SEQ / 32, NKVH), 512, 0, stream>>>(
        qkv, sinks, cosp, sinp, attn_b);

    // output projection. Tile 64x96, grid 32x16 = 512 (Npad 3072, cols >= 2880 masked).
    gemm_bal<64, 96, 2><<<dim3(WO_NPAD / 96, SEQ / 64), 512, 0, stream>>>(
        attn_b, woT, b_o, (float*)d_out, ATTN_N, HID, HID);
}